// Round 4
// baseline (200.847 us; speedup 1.0000x reference)
//
#include <hip/hip_runtime.h>

typedef __attribute__((ext_vector_type(8))) short bf16x8;
typedef __attribute__((ext_vector_type(4))) float f32x4;

// ---------------------------------------------------------------------------
// Posit(8,1) round-to-nearest quantization, bit-exact vs the jnp reference.
// two_es=2, npat=6, maxpos=2^12, minpos=2^-12. Result has <=4 fraction bits ->
// exactly representable in bf16 (and fp32).
// ---------------------------------------------------------------------------
__device__ __forceinline__ float posit_q(float x) {
  float ax = fabsf(x);
  ax = fmaxf(ax, 0x1p-12f);
  ax = fminf(ax, 0x1p12f);
  int s = (int)(__float_as_uint(ax) >> 23) - 127;   // floor(log2(ax)), exact
  int k = s >> 1;                                   // floor(s/2)
  int rlen = (k >= 0) ? (k + 2) : (1 - k);
  int fbits = 6 - rlen;
  fbits = fbits < 0 ? 0 : fbits;
  float m = ax * __uint_as_float((unsigned)(127 - s) << 23);  // [1,2)
  float fs = (float)(1 << fbits);
  float inv_fs = __uint_as_float((unsigned)(127 - fbits) << 23);
  float mq = rintf(m * fs) * inv_fs;                // round-half-even = jnp.round
  if (mq >= 2.0f) { s += 1; mq = 1.0f; }            // mantissa carry
  float y = mq * __uint_as_float((unsigned)(127 + s) << 23);
  y = fminf(y, 0x1p12f);
  y = copysignf(y, x);
  return (x == 0.0f) ? 0.0f : y;
}

__device__ __forceinline__ ushort4 quant4_bf16(float4 v) {
  ushort4 o;
  o.x = (ushort)(__float_as_uint(posit_q(v.x)) >> 16);
  o.y = (ushort)(__float_as_uint(posit_q(v.y)) >> 16);
  o.z = (ushort)(__float_as_uint(posit_q(v.z)) >> 16);
  o.w = (ushort)(__float_as_uint(posit_q(v.w)) >> 16);
  return o;
}

// One merged quantize kernel: x -> bf16, w -> bf16, bias -> fp32.
__global__ void posit_quant_all(const float* __restrict__ x,
                                const float* __restrict__ w,
                                const float* __restrict__ b,
                                ushort* __restrict__ Xq,
                                ushort* __restrict__ Wq,
                                float* __restrict__ bq,
                                int nx4, int nw4, int nb4) {
  int i = blockIdx.x * blockDim.x + threadIdx.x;
  if (i < nx4) {
    ((ushort4*)Xq)[i] = quant4_bf16(((const float4*)x)[i]);
  } else if (i < nx4 + nw4) {
    int j = i - nx4;
    ((ushort4*)Wq)[j] = quant4_bf16(((const float4*)w)[j]);
  } else if (i < nx4 + nw4 + nb4) {
    int j = i - nx4 - nw4;
    float4 v = ((const float4*)b)[j];
    float4 o;
    o.x = posit_q(v.x); o.y = posit_q(v.y);
    o.z = posit_q(v.z); o.w = posit_q(v.w);
    ((float4*)bq)[j] = o;
  }
}

// ---------------------------------------------------------------------------
// bf16 NT GEMM (A: MxK row-major, B: NxK row-major), C = A*B^T + bias.
// 128x128 tile, BK=32, ping-pong double-buffered K-loop (R4): loads for tile
// k+1 are issued BEFORE compute on tile k; the single per-iteration barrier
// (whose compiler-emitted vmcnt(0) drain is unavoidable) therefore lands
// AFTER ~16 MFMA of same-wave work, hiding the staging latency instead of
// exposing it. One barrier per 16 MFMA, drain nearly free.
// LDS 2 x 16 KB = 32 KB (same as R3 -> occupancy unchanged, 4 blocks/CU).
//
// Swizzle (BK=32, verified 0 conflicts in R2): 16B k-chunk at position p in
// row r stored at p ^ ((r>>1)&3); each 16-lane fragment-read quad covers all
// 8 bank-groups exactly twice (2-way = free). Staging lanes read a permuted
// chunk of the same 64 B row segment -> coalescing preserved and
// global_load_lds dests stay lane-contiguous.
// ---------------------------------------------------------------------------
__device__ __forceinline__ void gl_lds16(const ushort* g, ushort* l) {
  __builtin_amdgcn_global_load_lds(
      (const __attribute__((address_space(1))) void*)g,
      (__attribute__((address_space(3))) void*)l,
      16, 0, 0);
}

__global__ __launch_bounds__(256, 2) void posit_gemm(
    const ushort* __restrict__ A, const ushort* __restrict__ B,
    const float* __restrict__ bq, float* __restrict__ C,
    int M, int N, int K) {
  // [buf][A:4096 | B:4096] ushorts; buf stride 8192 elems (16 KB)
  __shared__ ushort lds[2 * 8192];

  const int tid = threadIdx.x;
  const int wave = tid >> 6;
  const int lane = tid & 63;
  const int wm = wave >> 1;         // 2x2 wave grid, 64x64 per wave
  const int wn = wave & 1;
  const int m0 = blockIdx.y << 7;
  const int n0 = blockIdx.x << 7;

  // staging: chunk c = 8 bf16 = 16 B; lds dest = wave-uniform base + lane*16.
  const int c0 = (wave << 6) + lane;             // 0..255 (round 0)
  const int r0 = c0 >> 2;                        // tile row 0..63
  const int p0 = c0 & 3;                         // LDS chunk position
  const int q0 = ((p0 ^ ((r0 >> 1) & 3)) << 3);  // swizzled global k-offset
  const int ldsoff = wave << 9;                  // within-buffer wave base

  const ushort* Ag0 = A + (size_t)(m0 + r0) * K + q0;
  const ushort* Ag1 = A + (size_t)(m0 + r0 + 64) * K + q0;
  const ushort* Bg0 = B + (size_t)(n0 + r0) * K + q0;
  const ushort* Bg1 = B + (size_t)(n0 + r0 + 64) * K + q0;

  const int fr = lane & 15;                      // fragment row (m or n)
  const int t4 = lane >> 4;
  const int fkp = ((t4 ^ ((fr >> 1) & 3)) << 3); // swizzled fragment k-chunk

  f32x4 acc[4][4];
#pragma unroll
  for (int i = 0; i < 4; i++)
#pragma unroll
    for (int j = 0; j < 4; j++) acc[i][j] = (f32x4){0.f, 0.f, 0.f, 0.f};

  auto stage = [&](int buf, int k0) {
    ushort* a = lds + (buf << 13) + ldsoff;
    ushort* b = a + 4096;
    gl_lds16(Ag0 + k0, a);
    gl_lds16(Ag1 + k0, a + 2048);
    gl_lds16(Bg0 + k0, b);
    gl_lds16(Bg1 + k0, b + 2048);
  };

  auto compute = [&](int buf) {
    const ushort* a = lds + (buf << 13);
    const ushort* b = a + 4096;
    bf16x8 fa[4], fb[4];
#pragma unroll
    for (int i = 0; i < 4; i++)
      fa[i] = *(const bf16x8*)(a + (((wm << 6) + (i << 4) + fr) << 5) + fkp);
#pragma unroll
    for (int j = 0; j < 4; j++)
      fb[j] = *(const bf16x8*)(b + (((wn << 6) + (j << 4) + fr) << 5) + fkp);
#pragma unroll
    for (int i = 0; i < 4; i++)
#pragma unroll
      for (int j = 0; j < 4; j++)
        acc[i][j] = __builtin_amdgcn_mfma_f32_16x16x32_bf16(
            fa[i], fb[j], acc[i][j], 0, 0, 0);
  };

  // Prologue: tile 0 into buf0. (K assumed multiple of 64; holds for 2048.)
  stage(0, 0);
  __syncthreads();

  for (int k0 = 0; k0 < K; k0 += 64) {
    stage(1, k0 + 32);           // prefetch odd tile (k0+32 < K always)
    compute(0);                  // tile k0 from buf0
    __syncthreads();             // drains lgkm (ds reads) + vmcnt (buf1 loads)
    if (k0 + 64 < K) stage(0, k0 + 64);  // prefetch next even tile
    compute(1);                  // tile k0+32 from buf1
    __syncthreads();
  }

  // Epilogue: C/D layout col = lane&15, row = (lane>>4)*4 + reg. Fuse bias.
  const int row0 = m0 + (wm << 6) + (t4 << 2);
  const int col0 = n0 + (wn << 6) + fr;
#pragma unroll
  for (int j = 0; j < 4; j++) {
    const int col = col0 + (j << 4);
    const float bv = bq[col];
#pragma unroll
    for (int i = 0; i < 4; i++) {
      const int row = row0 + (i << 4);
#pragma unroll
      for (int r = 0; r < 4; r++)
        C[(size_t)(row + r) * N + col] = acc[i][j][r] + bv;
    }
  }
}

extern "C" void kernel_launch(void* const* d_in, const int* in_sizes, int n_in,
                              void* d_out, int out_size, void* d_ws, size_t ws_size,
                              hipStream_t stream) {
  const float* x = (const float*)d_in[0];
  const float* w = (const float*)d_in[1];
  const float* bias = (const float*)d_in[2];
  float* out = (float*)d_out;

  const int out_f = in_sizes[2];                 // 2048
  const int in_f = in_sizes[1] / out_f;          // 2048
  const int m = in_sizes[0] / in_f;              // 8192
  const int k = in_f;

  // workspace layout: Xq bf16 | Wq bf16 | bq fp32
  ushort* Xq = (ushort*)d_ws;
  ushort* Wq = Xq + (size_t)m * k;
  float* bquant = (float*)(Wq + (size_t)out_f * k);

  const int nx4 = in_sizes[0] / 4;
  const int nw4 = in_sizes[1] / 4;
  const int nb4 = in_sizes[2] / 4;
  const int total4 = nx4 + nw4 + nb4;
  posit_quant_all<<<(total4 + 255) / 256, 256, 0, stream>>>(
      x, w, bias, Xq, Wq, bquant, nx4, nw4, nb4);

  dim3 grid(out_f / 128, m / 128);
  posit_gemm<<<grid, 256, 0, stream>>>(Xq, Wq, bquant, out, m, out_f, k);
}

// Round 5
// 184.714 us; speedup vs baseline: 1.0873x; 1.0873x over previous
//
#include <hip/hip_runtime.h>

typedef __attribute__((ext_vector_type(8))) short bf16x8;
typedef __attribute__((ext_vector_type(4))) float f32x4;

// ---------------------------------------------------------------------------
// Posit(8,1) round-to-nearest quantization, bit-exact vs the jnp reference.
// two_es=2, npat=6, maxpos=2^12, minpos=2^-12. Result has <=4 fraction bits ->
// exactly representable in bf16 (and fp32).
// ---------------------------------------------------------------------------
__device__ __forceinline__ float posit_q(float x) {
  float ax = fabsf(x);
  ax = fmaxf(ax, 0x1p-12f);
  ax = fminf(ax, 0x1p12f);
  int s = (int)(__float_as_uint(ax) >> 23) - 127;   // floor(log2(ax)), exact
  int k = s >> 1;                                   // floor(s/2)
  int rlen = (k >= 0) ? (k + 2) : (1 - k);
  int fbits = 6 - rlen;
  fbits = fbits < 0 ? 0 : fbits;
  float m = ax * __uint_as_float((unsigned)(127 - s) << 23);  // [1,2)
  float fs = (float)(1 << fbits);
  float inv_fs = __uint_as_float((unsigned)(127 - fbits) << 23);
  float mq = rintf(m * fs) * inv_fs;                // round-half-even = jnp.round
  if (mq >= 2.0f) { s += 1; mq = 1.0f; }            // mantissa carry
  float y = mq * __uint_as_float((unsigned)(127 + s) << 23);
  y = fminf(y, 0x1p12f);
  y = copysignf(y, x);
  return (x == 0.0f) ? 0.0f : y;
}

__device__ __forceinline__ ushort4 quant4_bf16(float4 v) {
  ushort4 o;
  o.x = (ushort)(__float_as_uint(posit_q(v.x)) >> 16);
  o.y = (ushort)(__float_as_uint(posit_q(v.y)) >> 16);
  o.z = (ushort)(__float_as_uint(posit_q(v.z)) >> 16);
  o.w = (ushort)(__float_as_uint(posit_q(v.w)) >> 16);
  return o;
}

// One merged quantize kernel: x -> bf16, w -> bf16, bias -> fp32.
__global__ void posit_quant_all(const float* __restrict__ x,
                                const float* __restrict__ w,
                                const float* __restrict__ b,
                                ushort* __restrict__ Xq,
                                ushort* __restrict__ Wq,
                                float* __restrict__ bq,
                                int nx4, int nw4, int nb4) {
  int i = blockIdx.x * blockDim.x + threadIdx.x;
  if (i < nx4) {
    ((ushort4*)Xq)[i] = quant4_bf16(((const float4*)x)[i]);
  } else if (i < nx4 + nw4) {
    int j = i - nx4;
    ((ushort4*)Wq)[j] = quant4_bf16(((const float4*)w)[j]);
  } else if (i < nx4 + nw4 + nb4) {
    int j = i - nx4 - nw4;
    float4 v = ((const float4*)b)[j];
    float4 o;
    o.x = posit_q(v.x); o.y = posit_q(v.y);
    o.z = posit_q(v.z); o.w = posit_q(v.w);
    ((float4*)bq)[j] = o;
  }
}

// ---------------------------------------------------------------------------
// bf16 NT GEMM (A: MxK row-major, B: NxK row-major), C = A*B^T + bias.
// R5: 256x128 tile, 512 threads (8 waves, 4x2 grid, 64x64 per wave), BK=64,
// single-buffered R3 structure (R4's ping-pong regressed: __syncthreads drains
// vmcnt(0) including the just-issued prefetch -> 2 full drains per 64-k vs 1).
// Rationale: at 128x128 the L2 staging floor (1 GB @ 36 TB/s) coincides with
// the MFMA floor; 256x128 cuts staged traffic to 768 MB (-25%) and doubles
// per-block waves for cross-block drain hiding. LDS 48 KB -> 2 blocks/CU
// (grid 512 = exactly 2/CU), 16 waves/CU.
//
// Swizzle (BK=64, measured 0 conflicts in R3): 16B k-chunk at position p of
// row r stored at p ^ (r&7); row&7 == lane>>3 for staging lanes and == fr&7
// for fragment readers (row bases are multiples of 16). Staging 8-lane groups
// read one row's 128 B segment permuted within itself -> coalesced; lds dests
// lane-contiguous as global_load_lds requires.
// ---------------------------------------------------------------------------
__device__ __forceinline__ void gl_lds16(const ushort* g, ushort* l) {
  __builtin_amdgcn_global_load_lds(
      (const __attribute__((address_space(1))) void*)g,
      (__attribute__((address_space(3))) void*)l,
      16, 0, 0);
}

__global__ __launch_bounds__(512, 4) void posit_gemm(
    const ushort* __restrict__ A, const ushort* __restrict__ B,
    const float* __restrict__ bq, float* __restrict__ C,
    int M, int N, int K) {
  __shared__ ushort sA[256 * 64];   // 32 KB, row-major [256][64], chunk-swizzled
  __shared__ ushort sB[128 * 64];   // 16 KB

  const int tid = threadIdx.x;
  const int wave = tid >> 6;        // 0..7
  const int lane = tid & 63;
  const int wm = wave >> 1;         // 4x2 wave grid: wm 0..3, wn 0..1
  const int wn = wave & 1;
  const int m0 = blockIdx.y << 8;   // 256-row tiles
  const int n0 = blockIdx.x << 7;   // 128-col tiles

  // --- staging: chunk c = round*512 + wave*64 + lane; row = c>>3 (64 rows
  // per round), pos = lane&7, row&7 = lane>>3 (wave- and round-independent).
  const int g8 = lane >> 3;                       // 0..7
  const int qe = ((lane & 7) ^ g8) << 3;          // swizzled k-elem offset [0,64)
  const int rb = (wave << 3) + g8;                // row within 64-row round

  const ushort* Ag = A + (size_t)(m0 + rb) * K + qe;
  const ushort* Bg = B + (size_t)(n0 + rb) * K + qe;
  const size_t rstep = (size_t)64 * K;            // 64 rows per round

  // wave-uniform LDS bases per round (HW adds lane*16 B)
  const int wbase = wave << 9;                    // wave*512 elems
  ushort* lA0 = sA + wbase;                       // A rounds 0..3
  ushort* lB0 = sB + wbase;                       // B rounds 0..1

  // --- fragment reads: row = w?*64 + i*16 + fr; k-chunk p = kk*4 + t4,
  // stored at p ^ (fr&7).
  const int fr = lane & 15;
  const int t4 = lane >> 4;                       // 0..3
  const int pk0 = ((t4 ^ (fr & 7)) << 3);
  const int pk1 = (((4 + t4) ^ (fr & 7)) << 3);

  f32x4 acc[4][4];
#pragma unroll
  for (int i = 0; i < 4; i++)
#pragma unroll
    for (int j = 0; j < 4; j++) acc[i][j] = (f32x4){0.f, 0.f, 0.f, 0.f};

  for (int k0 = 0; k0 < K; k0 += 64) {
#pragma unroll
    for (int r = 0; r < 4; r++)
      gl_lds16(Ag + k0 + r * rstep, lA0 + (r << 12));
#pragma unroll
    for (int r = 0; r < 2; r++)
      gl_lds16(Bg + k0 + r * rstep, lB0 + (r << 12));
    __syncthreads();                  // single vmcnt drain per 64-k

#pragma unroll
    for (int kk = 0; kk < 2; kk++) {
      const int pk = kk ? pk1 : pk0;
      bf16x8 fa[4], fb[4];
#pragma unroll
      for (int i = 0; i < 4; i++)
        fa[i] = *(const bf16x8*)(sA + (((wm << 6) + (i << 4) + fr) << 6) + pk);
#pragma unroll
      for (int j = 0; j < 4; j++)
        fb[j] = *(const bf16x8*)(sB + (((wn << 6) + (j << 4) + fr) << 6) + pk);

#pragma unroll
      for (int i = 0; i < 4; i++)
#pragma unroll
        for (int j = 0; j < 4; j++)
          acc[i][j] = __builtin_amdgcn_mfma_f32_16x16x32_bf16(
              fa[i], fb[j], acc[i][j], 0, 0, 0);
    }
    __syncthreads();
  }

  // Epilogue: C/D layout col = lane&15, row = (lane>>4)*4 + reg. Fuse bias.
  const int row0 = m0 + (wm << 6) + (t4 << 2);
  const int col0 = n0 + (wn << 6) + fr;
#pragma unroll
  for (int j = 0; j < 4; j++) {
    const int col = col0 + (j << 4);
    const float bv = bq[col];
#pragma unroll
    for (int i = 0; i < 4; i++) {
      const int row = row0 + (i << 4);
#pragma unroll
      for (int r = 0; r < 4; r++)
        C[(size_t)(row + r) * N + col] = acc[i][j][r] + bv;
    }
  }
}

extern "C" void kernel_launch(void* const* d_in, const int* in_sizes, int n_in,
                              void* d_out, int out_size, void* d_ws, size_t ws_size,
                              hipStream_t stream) {
  const float* x = (const float*)d_in[0];
  const float* w = (const float*)d_in[1];
  const float* bias = (const float*)d_in[2];
  float* out = (float*)d_out;

  const int out_f = in_sizes[2];                 // 2048
  const int in_f = in_sizes[1] / out_f;          // 2048
  const int m = in_sizes[0] / in_f;              // 8192
  const int k = in_f;

  // workspace layout: Xq bf16 | Wq bf16 | bq fp32
  ushort* Xq = (ushort*)d_ws;
  ushort* Wq = Xq + (size_t)m * k;
  float* bquant = (float*)(Wq + (size_t)out_f * k);

  const int nx4 = in_sizes[0] / 4;
  const int nw4 = in_sizes[1] / 4;
  const int nb4 = in_sizes[2] / 4;
  const int total4 = nx4 + nw4 + nb4;
  posit_quant_all<<<(total4 + 255) / 256, 256, 0, stream>>>(
      x, w, bias, Xq, Wq, bquant, nx4, nw4, nb4);

  dim3 grid(out_f / 128, m / 256);
  posit_gemm<<<grid, 512, 0, stream>>>(Xq, Wq, bquant, out, m, out_f, k);
}